// Round 7
// baseline (38.869 us; speedup 1.0000x reference)
//
#include <hip/hip_runtime.h>

#define H2C 450
#define WC 1242
#define HC 375
#define NPTS 4000000
#define NPIX (H2C * WC)   // 558900
#define TPB 256

// d_ws layout: [0..16) floats: M = Pc @ inv(Pl); winner int[NPIX] at byte 256.

// rows 0..2 of A@B (4x4), k-sequential FMA chain == mm4 rows 0-2 bit-exactly (rounds 1-6).
__device__ __forceinline__ void rows3(const float* __restrict__ A, const float* __restrict__ B,
                                      float* o12) {
#pragma unroll
    for (int i = 0; i < 3; i++)
#pragma unroll
        for (int j = 0; j < 4; j++) {
            float t = A[i * 4 + 0] * B[0 * 4 + j];
            t = fmaf(A[i * 4 + 1], B[1 * 4 + j], t);
            t = fmaf(A[i * 4 + 2], B[2 * 4 + j], t);
            t = fmaf(A[i * 4 + 3], B[3 * 4 + j], t);
            o12[i * 4 + j] = t;
        }
}

__device__ __forceinline__ void mm4(float* o, const float* a, const float* b) {
    // full 4x4 a@b, same chain. Bit-identical to rounds 1-6.
#pragma unroll
    for (int i = 0; i < 4; i++)
#pragma unroll
        for (int j = 0; j < 4; j++) {
            float t = a[i * 4 + 0] * b[0 * 4 + j];
            t = fmaf(a[i * 4 + 1], b[1 * 4 + j], t);
            t = fmaf(a[i * 4 + 2], b[2 * 4 + j], t);
            t = fmaf(a[i * 4 + 3], b[3 * 4 + j], t);
            o[i * 4 + j] = t;
        }
}

// Register-resident LAPACK sgetrf/getrs replica (r5-proven). Computes M = Pc @ inv(Pl)
// and writes ONLY M (16 floats). Bit-identical arithmetic to rounds 1-6.
__device__ void compute_M(const float* K, const float* C, const float* L, float* outM) {
#pragma clang fp contract(off)
    float Pc[16], Pl[16], A[16], X[16], M[16];
    int piv[4];
    mm4(Pc, K, C);
    mm4(Pl, K, L);
#pragma unroll
    for (int k = 0; k < 16; k++) A[k] = Pl[k];

#pragma unroll
    for (int k = 0; k < 4; k++) {
        int p = k; float mx = fabsf(A[k * 4 + k]);
#pragma unroll
        for (int r = k + 1; r < 4; r++) {
            float v = fabsf(A[r * 4 + k]);
            if (v > mx) { mx = v; p = r; }
        }
        piv[k] = p;
#pragma unroll
        for (int r = k + 1; r < 4; r++) {
            bool sw = (p == r);
#pragma unroll
            for (int j = 0; j < 4; j++) {
                float tk = A[k * 4 + j], tr = A[r * 4 + j];
                A[k * 4 + j] = sw ? tr : tk;
                A[r * 4 + j] = sw ? tk : tr;
            }
        }
        float akk = A[k * 4 + k];
        if (fabsf(akk) >= 1.17549435e-38f) {
            float rr = 1.0f / akk;
#pragma unroll
            for (int r2 = k + 1; r2 < 4; r2++) A[r2 * 4 + k] = A[r2 * 4 + k] * rr;
        } else {
#pragma unroll
            for (int r2 = k + 1; r2 < 4; r2++) A[r2 * 4 + k] = A[r2 * 4 + k] / akk;
        }
#pragma unroll
        for (int r = k + 1; r < 4; r++) {
            float lik = A[r * 4 + k];
#pragma unroll
            for (int j = k + 1; j < 4; j++) A[r * 4 + j] = A[r * 4 + j] - lik * A[k * 4 + j];
        }
    }

#pragma unroll
    for (int k = 0; k < 16; k++) X[k] = 0.0f;
    X[0] = X[5] = X[10] = X[15] = 1.0f;
#pragma unroll
    for (int k = 0; k < 4; k++) {
        int p = piv[k];
#pragma unroll
        for (int r = k + 1; r < 4; r++) {
            bool sw = (p == r);
#pragma unroll
            for (int j = 0; j < 4; j++) {
                float tk = X[k * 4 + j], tr = X[r * 4 + j];
                X[k * 4 + j] = sw ? tr : tk;
                X[r * 4 + j] = sw ? tk : tr;
            }
        }
    }
#pragma unroll
    for (int j = 0; j < 4; j++) {
#pragma unroll
        for (int k = 0; k < 4; k++) {
            float xk = X[k * 4 + j];
#pragma unroll
            for (int r = k + 1; r < 4; r++) X[r * 4 + j] = X[r * 4 + j] - xk * A[r * 4 + k];
        }
#pragma unroll
        for (int k = 3; k >= 0; k--) {
            float xk = X[k * 4 + j] / A[k * 4 + k];
            X[k * 4 + j] = xk;
#pragma unroll
            for (int r = 0; r < k; r++) X[r * 4 + j] = X[r * 4 + j] - xk * A[r * 4 + k];
        }
    }
    mm4(M, Pc, X);
#pragma unroll
    for (int k = 0; k < 16; k++) outM[k] = M[k];
}

// 1 pt/thread streaming pass. Pc/Pl rows computed per-thread (no barrier, no LDS).
// Global thread 0 additionally runs the register-LU and publishes M for resolve_k
// (one diverged wave out of 62500 -> zero duration impact). fi zero-fill fused.
__global__ void __launch_bounds__(TPB)
point_k(const float4* __restrict__ velo, const float* __restrict__ K,
        const float* __restrict__ C, const float* __restrict__ L,
        int* __restrict__ winner, float* __restrict__ fi, float* __restrict__ gM) {
    float pc[12], pl[12];
    rows3(K, C, pc);
    rows3(K, L, pl);
    int i = blockIdx.x * TPB + threadIdx.x;   // grid is exactly NPTS threads
    if (i == 0) compute_M(K, C, L, gM);
    fi[i] = 0.0f;   // resolve_k overwrites winners afterwards
    float4 v = velo[i];
    float vp0 = fmaf(v.w, pc[3],  fmaf(v.z, pc[2],  fmaf(v.y, pc[1], v.x * pc[0])));
    float vp1 = fmaf(v.w, pc[7],  fmaf(v.z, pc[6],  fmaf(v.y, pc[5], v.x * pc[4])));
    float vz  = fmaf(v.w, pc[11], fmaf(v.z, pc[10], fmaf(v.y, pc[9], v.x * pc[8])));
    float vx = vp0 / vz;
    float vy = vp1 / vz;
    bool onimg = (v.x > 0.f) && (vx > 0.f) && (vx < (float)WC) && (vy > 0.f) && (vy < (float)HC);
    float nv0 = fmaf(v.w, pl[3],  fmaf(v.z, pl[2],  fmaf(v.y, pl[1], v.x * pl[0])));
    float nv1 = fmaf(v.w, pl[7],  fmaf(v.z, pl[6],  fmaf(v.y, pl[5], v.x * pl[4])));
    float nz  = fmaf(v.w, pl[11], fmaf(v.z, pl[10], fmaf(v.y, pl[9], v.x * pl[8])));
    float nx = nv0 / nz;
    float ny = nv1 / nz;
    float rx = rintf(nx);   // round half to even == jnp.round
    float ry = rintf(ny);
    // float-domain bounds checks reproduce numpy int32-cast outcomes (NaN/huge -> invalid)
    if (onimg && (nz > 0.f) && (rx >= 0.f) && (rx < (float)WC) && (ry >= 0.f) && (ry < (float)H2C)) {
        int px = (int)rx, py = (int)ry;
        atomicMax(&winner[py * WC + px], i);   // last-write-wins == max index wins
    }
}

__global__ void __launch_bounds__(TPB)
resolve_k(const float* __restrict__ depth, const float4* __restrict__ velo,
          const float* __restrict__ K, const float* __restrict__ C,
          const float* __restrict__ L, const float* __restrict__ gM,
          const int* __restrict__ winner,
          float* __restrict__ img, float* __restrict__ noocc,
          float* __restrict__ org, float* __restrict__ fi) {
#pragma clang fp contract(off)
    __shared__ float srec[TPB * 7];
    int pb = blockIdx.x * TPB;
    int p = pb + threadIdx.x;
    int valid = NPIX - pb; if (valid > TPB) valid = TPB;
    float o0 = 0.f, o1 = 0.f, o2 = 0.f, o3 = 0.f, o4 = 0.f, o5 = 0.f, o6 = 0.f;
    if (p < NPIX) {
        int wi = winner[p];
        if (wi >= 0) {
            // rare branch (~hundreds of pixels): per-thread Pc/Pl is negligible here
            float pc[12], pl[12];
            rows3(K, C, pc);
            rows3(K, L, pl);
            float4 v = velo[wi];
            float vp0 = fmaf(v.w, pc[3],  fmaf(v.z, pc[2],  fmaf(v.y, pc[1], v.x * pc[0])));
            float vp1 = fmaf(v.w, pc[7],  fmaf(v.z, pc[6],  fmaf(v.y, pc[5], v.x * pc[4])));
            float vz  = fmaf(v.w, pc[11], fmaf(v.z, pc[10], fmaf(v.y, pc[9], v.x * pc[8])));
            float nv0 = fmaf(v.w, pl[3],  fmaf(v.z, pl[2],  fmaf(v.y, pl[1], v.x * pl[0])));
            float nv1 = fmaf(v.w, pl[7],  fmaf(v.z, pl[6],  fmaf(v.y, pl[5], v.x * pl[4])));
            float nz  = fmaf(v.w, pl[11], fmaf(v.z, pl[10], fmaf(v.y, pl[9], v.x * pl[8])));
            o0 = nv0 / nz; o1 = nv1 / nz; o2 = nz;
            o3 = vp0 / vz; o4 = vp1 / vz; o5 = vz;
            o6 = (float)wi;
            noocc[p] = 1.0f;
            org[p] = 1.0f;
            fi[wi] = 1.0f;   // winners unique per pixel -> no conflict
        } else {
            noocc[p] = 0.0f;
            org[p] = 0.0f;
            float d = depth[p];
            if (d > 0.0f) {
                int y = p / WC, x = p - y * WC;
                float fx = (float)x, fy = (float)y;
                float p0 = fx * d, p1 = fy * d;
                // np.einsum: plain left-to-right mul/add, no FMA (contract off above)
                float pp0 = ((p0 * gM[0] + p1 * gM[1]) + d * gM[2]) + gM[3];
                float pp1 = ((p0 * gM[4] + p1 * gM[5]) + d * gM[6]) + gM[7];
                float pp2 = ((p0 * gM[8] + p1 * gM[9]) + d * gM[10]) + gM[11];
                float zs = (pp2 != 0.0f) ? pp2 : 1.0f;
                o0 = fx; o1 = fy; o2 = d;
                o3 = pp0 / zs; o4 = pp1 / zs; o5 = pp2;
                o6 = 0.0f;
            }
        }
    }
    // stage the 7-float record in LDS, then write back fully coalesced
    float* r = srec + threadIdx.x * 7;
    r[0] = o0; r[1] = o1; r[2] = o2; r[3] = o3; r[4] = o4; r[5] = o5; r[6] = o6;
    __syncthreads();
    float* obase = img + (size_t)pb * 7;
    int nfl = valid * 7;
    for (int k = threadIdx.x; k < nfl; k += TPB) obase[k] = srec[k];
}

extern "C" void kernel_launch(void* const* d_in, const int* in_sizes, int n_in,
                              void* d_out, int out_size, void* d_ws, size_t ws_size,
                              hipStream_t stream) {
    const float* velo  = (const float*)d_in[0];
    const float* K     = (const float*)d_in[1];
    const float* C     = (const float*)d_in[2];
    const float* L     = (const float*)d_in[3];
    const float* depth = (const float*)d_in[4];

    float* out   = (float*)d_out;
    float* img   = out;                       // NPIX*7
    float* noocc = out + (size_t)NPIX * 7;    // NPIX
    float* org   = noocc + NPIX;              // NPIX
    float* fi    = org + NPIX;                // NPTS

    float* gM    = (float*)d_ws;
    int* winner  = (int*)((char*)d_ws + 256);

    // 0xFF bytes == int32 -1 sentinel (capture-safe memset node, proven r4/r6)
    hipMemsetAsync(winner, 0xFF, (size_t)NPIX * sizeof(int), stream);

    point_k<<<NPTS / TPB, TPB, 0, stream>>>((const float4*)velo, K, C, L, winner, fi, gM);

    resolve_k<<<(NPIX + TPB - 1) / TPB, TPB, 0, stream>>>(depth, (const float4*)velo, K, C, L,
                                                          gM, winner, img, noocc, org, fi);
}